// Round 3
// baseline (191.214 us; speedup 1.0000x reference)
//
#include <hip/hip_runtime.h>

// Correlation layer: out[b,o,h,w] = mean_c x1[b,c,h,w] * x2[b,c,h+dh,w+dw]
// B=8 C=128 H=W=128, d=4 -> 81 offsets (o = (dh+4)*9 + (dw+4)).
//
// R3 changes vs R2 (86 us, VALUBusy 34%, LDS ~55%, neither pipe saturated ->
// per-channel __syncthreads coupling is the residual):
//  - staging is WAVE-PRIVATE: each wave stages its own 4 x2 rows (2 out rows
//    + 2 halo) into its own LDS region; all main-loop sync is intra-wave
//    lgkmcnt (DS ops in-order per wave). ZERO barriers in the channel loop.
//  - wave w of 4: half=w>>1 (channel split c0/c64), rowpair=w&1 (rows 2rp,2rp+1)
//  - keep: register prefetch (1-iter slack), XCD swizzle (batch per XCD)

constexpr int Bn = 8, Cn = 128, Hn = 128, Wn = 128;
constexpr int HWn = Hn * Wn;
constexpr int TH = 4;            // output rows per WG tile
constexpr int NDH = 3;           // dh values per group
constexpr int WR = 4;            // staged x2 rows per wave = 2 + NDH - 1
constexpr int WP = 144;          // padded LDS row: cols -4..135 at idx 0..139

__global__ __launch_bounds__(256, 3)
void corr_kernel(const float* __restrict__ x1, const float* __restrict__ x2,
                 float* __restrict__ out) {
  __shared__ float s2[4][WR][WP]; // per-wave private staging (9.2 KB)
  __shared__ float sred[128][36]; // cross-half reduction buffer (18.4 KB)

  const int t    = threadIdx.x;
  const int wv   = t >> 6;            // wave 0..3
  const int lane = t & 63;
  const int half = wv >> 1;           // 0: c 0..63, 1: c 64..127
  const int rp   = wv & 1;            // row pair within tile
  const int q    = t & 127;           // reduction pairing index
  const int rowl = q >> 5;            // local out row 0..3 (== 2*rp + (lane>>5))
  const int w0   = (lane & 31) << 2;  // 0,4,...,124

  // --- XCD swizzle: batch b lives on XCD b (round-robin assumption; perf-only) ---
  const int phys = blockIdx.x;        // 0..767
  const int xcd  = phys & 7;
  const int slot = phys >> 3;         // 0..95
  const int tl   = slot / 3;          // 0..31
  const int g    = slot % 3;          // dh group
  const int tile = xcd * 32 + tl;
  const int b    = tile >> 5;         // == xcd
  const int h0   = (tile & 31) * TH;
  const int dhm  = g * NDH - 4;       // first dh of group: -4, -1, +2

  // --- wave-private staging: 4 rows x 35 float4 slots = 140 slots/wave ---
  const int base_row = h0 + 2 * rp + dhm;  // staged global row = base_row + sr
  const int s0i = lane, s1i = lane + 64, s2ii = lane + 128;
  const bool act2 = (lane < 12);           // 140 = 64 + 64 + 12
  const int sr0 = s0i / 35, fc0 = s0i % 35;
  const int sr1 = s1i / 35, fc1 = s1i % 35;
  const int sr2 = act2 ? s2ii / 35 : 0, fc2 = act2 ? s2ii % 35 : 0;
  const bool ok0 = ((unsigned)(base_row + sr0) < (unsigned)Hn) && (fc0 >= 1) && (fc0 <= 32);
  const bool ok1 = ((unsigned)(base_row + sr1) < (unsigned)Hn) && (fc1 >= 1) && (fc1 <= 32);
  const bool ok2 = act2 && ((unsigned)(base_row + sr2) < (unsigned)Hn) && (fc2 >= 1) && (fc2 <= 32);
  const int off0 = (base_row + sr0) * Wn + fc0 * 4 - 4;
  const int off1 = (base_row + sr1) * Wn + fc1 * 4 - 4;
  const int off2 = (base_row + sr2) * Wn + fc2 * 4 - 4;
  float* lp0 = &s2[wv][sr0][fc0 * 4];
  float* lp1 = &s2[wv][sr1][fc1 * 4];
  float* lp2 = &s2[wv][sr2][fc2 * 4];

  const float* x1c = x1 + ((size_t)b * Cn + half * 64) * HWn + (h0 + rowl) * Wn + w0;
  const float* x2c = x2 + ((size_t)b * Cn + half * 64) * HWn;

  float4 acc[NDH][9];
#pragma unroll
  for (int r = 0; r < NDH; ++r)
#pragma unroll
    for (int dw = 0; dw < 9; ++dw) acc[r][dw] = make_float4(0.f, 0.f, 0.f, 0.f);

  // --- prologue: prefetch channel 0 ---
  float4 pv0 = make_float4(0.f, 0.f, 0.f, 0.f);
  float4 pv1 = make_float4(0.f, 0.f, 0.f, 0.f);
  float4 pv2 = make_float4(0.f, 0.f, 0.f, 0.f);
  if (ok0) pv0 = *(const float4*)(x2c + off0);
  if (ok1) pv1 = *(const float4*)(x2c + off1);
  if (ok2) pv2 = *(const float4*)(x2c + off2);
  float4 pa = *(const float4*)x1c;

  const int srow_base = lane >> 5;    // 0 or 1: local row within staged block

#pragma unroll 1
  for (int cc = 0; cc < 64; ++cc) {
    // stage channel cc (regs loaded last iter -> vmcnt long satisfied)
    *(float4*)lp0 = pv0;
    *(float4*)lp1 = pv1;
    if (act2) *(float4*)lp2 = pv2;
    const float4 a = pa;
    // prefetch channel cc+1 (lands during this iter's compute)
    if (cc < 63) {
      const float* nx2 = x2c + (size_t)(cc + 1) * HWn;
      if (ok0) pv0 = *(const float4*)(nx2 + off0);
      if (ok1) pv1 = *(const float4*)(nx2 + off1);
      if (ok2) pv2 = *(const float4*)(nx2 + off2);
      pa = *(const float4*)(x1c + (size_t)(cc + 1) * HWn);
    }
    // window reads: wave-private region, DS in-order per wave => no barrier
#pragma unroll
    for (int r = 0; r < NDH; ++r) {
      const float* srow = &s2[wv][srow_base + r][w0];  // idx w0 == col w0-4
      const float4 wa = *(const float4*)(srow);
      const float4 wb = *(const float4*)(srow + 4);
      const float4 wc = *(const float4*)(srow + 8);
      const float win[12] = {wa.x, wa.y, wa.z, wa.w, wb.x, wb.y, wb.z, wb.w,
                             wc.x, wc.y, wc.z, wc.w};
      // pixel j (j=0..3) with offset dw-4 reads win[j+dw]
#pragma unroll
      for (int dw = 0; dw < 9; ++dw) {
        acc[r][dw].x += a.x * win[dw + 0];
        acc[r][dw].y += a.y * win[dw + 1];
        acc[r][dw].z += a.z * win[dw + 2];
        acc[r][dw].w += a.w * win[dw + 3];
      }
    }
  }

  // --- cross-half reduction + store (one-time; barriers OK here) ---
  const float scale = 1.0f / 128.0f;
  float* ob = out + (size_t)b * 81 * HWn + (size_t)(h0 + rowl) * Wn + w0;
#pragma unroll
  for (int r = 0; r < NDH; ++r) {
    if (half) {
#pragma unroll
      for (int dw = 0; dw < 9; ++dw) *(float4*)&sred[q][dw * 4] = acc[r][dw];
    }
    __syncthreads();
    if (!half) {
      const int obase = (g * 3 + r) * 9;
#pragma unroll
      for (int dw = 0; dw < 9; ++dw) {
        const float4 s = *(const float4*)&sred[q][dw * 4];
        const float4 m = acc[r][dw];
        float4 rz;
        rz.x = (m.x + s.x) * scale;
        rz.y = (m.y + s.y) * scale;
        rz.z = (m.z + s.z) * scale;
        rz.w = (m.w + s.w) * scale;
        *(float4*)(ob + (size_t)(obase + dw) * HWn) = rz;
      }
    }
    __syncthreads();
  }
}

extern "C" void kernel_launch(void* const* d_in, const int* in_sizes, int n_in,
                              void* d_out, int out_size, void* d_ws, size_t ws_size,
                              hipStream_t stream) {
  const float* x1 = (const float*)d_in[0];
  const float* x2 = (const float*)d_in[1];
  float* out = (float*)d_out;
  const int n_wgs = Bn * (Hn / TH) * 3;  // 768 = 3 per CU
  corr_kernel<<<dim3(n_wgs), dim3(256), 0, stream>>>(x1, x2, out);
}